// Round 4
// baseline (261.010 us; speedup 1.0000x reference)
//
#include <hip/hip_runtime.h>
#include <math.h>

typedef _Float16 half_t;
typedef _Float16 h2 __attribute__((ext_vector_type(2)));
typedef unsigned int uint;
typedef unsigned long long u64;

#define TPB 256

__device__ __forceinline__ uint pack_h2f(float a, float b) {
  half_t ha = (half_t)a, hb = (half_t)b;
  return (uint)__builtin_bit_cast(unsigned short, ha) |
         ((uint)__builtin_bit_cast(unsigned short, hb) << 16);
}

__device__ __forceinline__ float fdot2f(uint f, uint w, float acc) {
#if __has_builtin(__builtin_amdgcn_fdot2)
  return __builtin_amdgcn_fdot2(__builtin_bit_cast(h2, f),
                                __builtin_bit_cast(h2, w), acc, false);
#else
  h2 a = __builtin_bit_cast(h2, f), b = __builtin_bit_cast(h2, w);
  acc = fmaf((float)a.x, (float)b.x, acc);
  return fmaf((float)a.y, (float)b.y, acc);
#endif
}

struct Frag { uint d0, d1, d2, d3; float silu; };

// Uniform-knot cubic B-spline + silu, dense-8 fp16 fragment built IN REGISTERS:
// pack the 4 nonzero basis values into 64 bits, shift into place by 16*p within
// a 128-bit window (halves 0..7). Out-of-window halves drop off the shift ends,
// exactly matching the reference's 8-of-11 basis window clipping.
__device__ __forceinline__ Frag make_feat(float x) {
  Frag fr;
  float e = __expf(-x);
  fr.silu = x * __builtin_amdgcn_rcpf(1.0f + e);
  float s = fmaf(x, 2.5f, 5.5f);        // (x - (-2.2)) / 0.4
  float sf = floorf(s);
  float t = s - sf;
  int p = (int)sf - 3;                  // first nonzero basis index (may be <0)
  float omt = 1.0f - t, t2 = t * t;
  float B0 = (1.0f / 6.0f) * omt * omt * omt;
  float B3 = (1.0f / 6.0f) * t2 * t;
  float B1 = fmaf(0.5f * t, t2, 2.0f / 3.0f - t2);
  float B2 = 1.0f - B0 - B1 - B3;       // partition of unity
  u64 A = ((u64)pack_h2f(B2, B3) << 32) | pack_h2f(B0, B1);
  int n = p < 0 ? -p : 0;               // halves below 0: pre-drop
  A = (n >= 4) ? 0ull : (A >> (16 * n));
  int pc = p < 0 ? 0 : (p > 9 ? 9 : p);
  int sh = 16 * pc;                     // 0..144
  u64 lo = (sh < 64) ? (A << sh) : 0ull;
  u64 hi = (sh == 0) ? 0ull
         : (sh < 64) ? (A >> (64 - sh))
         : (sh < 128) ? (A << (sh - 64)) : 0ull;
  fr.d0 = (uint)lo; fr.d1 = (uint)(lo >> 32);
  fr.d2 = (uint)hi; fr.d3 = (uint)(hi >> 32);
  return fr;
}

// LDS (16.3 KB total):
//  WL[0,72):    L1 spline weights (sw*scaler), uint4 per (tap,o) at (tap*2+o)*4
//  WL[72,216):  L2 spline weights, uint4 at 72 + ci*72 + (tap*2+o)*4
//  F2: 2ci x 16x16 padded slots x 6dw (frag d0..d3, silu h2, pad)
//  P:  784 f32 partials (ci,o,pos,quad)
__global__ __launch_bounds__(TPB, 6) void kan_fwd(
    const float* __restrict__ x,
    const float* __restrict__ bw1, const float* __restrict__ sw1,
    const float* __restrict__ sc1,
    const float* __restrict__ bw2, const float* __restrict__ sw2,
    const float* __restrict__ sc2,
    float* __restrict__ out)
{
  __shared__ __align__(16) uint lds[216 + 3072 + 784];
  uint* WL = lds;
  uint* F2 = lds + 216;
  float* P = (float*)(lds + 216 + 3072);

  const int tid = threadIdx.x;
  const float* xb = x + (size_t)blockIdx.x * 784;

  // ---- Phase 0: pack spline weights into LDS; pre-fill F2 borders ----
  if (tid < 54) {
    int o, tap;
    uint* dst; const float* sw; float scv;
    if (tid < 18) {
      o = tid / 9; tap = tid - o * 9;
      dst = &WL[(tap * 2 + o) * 4]; sw = sw1 + tid * 8; scv = sc1[tid];
    } else {
      int q = tid - 18, wid = q / 9;
      tap = q - wid * 9; o = wid >> 1; int ci = wid & 1;
      dst = &WL[72 + ci * 72 + (tap * 2 + o) * 4]; sw = sw2 + q * 8; scv = sc2[q];
    }
#pragma unroll
    for (int j = 0; j < 4; ++j)
      dst[j] = pack_h2f(sw[2 * j] * scv, sw[2 * j + 1] * scv);
  }
  // features of x=0: basis halves 2..5 = {1/48, 23/48, 23/48, 1/48}, silu=0
  const uint F0d1 = pack_h2f(1.0f / 48.0f, 23.0f / 48.0f);
  const uint F0d2 = pack_h2f(23.0f / 48.0f, 1.0f / 48.0f);
  for (int i = tid; i < 512; i += TPB) {
    int rr = (i >> 4) & 15, cc = i & 15;
    if (rr == 0 || rr == 15 || cc == 0 || cc == 15) {
      uint* sl = &F2[i * 6];
      sl[0] = 0u; sl[1] = F0d1; sl[2] = F0d2; sl[3] = 0u; sl[4] = 0u;
    }
  }
  __syncthreads();

  const int wv = tid >> 6, lane = tid & 63;

  // ---- Phase A: L1 conv from REGISTER features (no F1 LDS), pool, F2 ----
  if (lane < 49) {
    const int quad = wv * 49 + lane;               // 0..195
    const int ph = quad / 14, pw = quad - (quad / 14) * 14;
    float xv[16];
#pragma unroll
    for (int r = 0; r < 4; ++r) {
      int ir = 2 * ph - 1 + r;
#pragma unroll
      for (int c = 0; c < 4; ++c) {
        int ic = 2 * pw - 1 + c;
        bool ok = ((uint)ir < 28u) & ((uint)ic < 28u);
        int idx = ok ? (ir * 28 + ic) : 0;
        float v = xb[idx];
        xv[r * 4 + c] = ok ? v : 0.0f;             // zero-pad
      }
    }
    float acc[2][4] = {};
#pragma unroll
    for (int r = 0; r < 4; ++r) {                  // rolling by window row
      Frag fr[4];
#pragma unroll
      for (int c = 0; c < 4; ++c) fr[c] = make_feat(xv[r * 4 + c]);
#pragma unroll
      for (int dh = 0; dh < 2; ++dh) {
        const int tr = r - dh;
        if (tr < 0 || tr > 2) continue;
#pragma unroll
        for (int tc = 0; tc < 3; ++tc) {
          const int tap = tr * 3 + tc;
#pragma unroll
          for (int o = 0; o < 2; ++o) {
            const uint4 w = *(const uint4*)&WL[(tap * 2 + o) * 4];
            const float bw = bw1[o * 9 + tap];     // uniform -> scalar load
#pragma unroll
            for (int dw = 0; dw < 2; ++dw) {
              const int c = tc + dw;
              float a = acc[o][dh * 2 + dw];
              a = fmaf(fr[c].silu, bw, a);
              a = fdot2f(fr[c].d0, w.x, a);
              a = fdot2f(fr[c].d1, w.y, a);
              a = fdot2f(fr[c].d2, w.z, a);
              a = fdot2f(fr[c].d3, w.w, a);
              acc[o][dh * 2 + dw] = a;
            }
          }
        }
      }
    }
#pragma unroll
    for (int o = 0; o < 2; ++o) {
      float m = fmaxf(fmaxf(acc[o][0], acc[o][1]), fmaxf(acc[o][2], acc[o][3]));
      Frag fm = make_feat(m);
      uint* sl = &F2[(o * 256 + (ph + 1) * 16 + (pw + 1)) * 6];
      sl[0] = fm.d0; sl[1] = fm.d1; sl[2] = fm.d2; sl[3] = fm.d3;
      sl[4] = pack_h2f(fm.silu, 0.0f);
    }
  }
  __syncthreads();

  // ---- Phase B: L2 conv; wave = ci (2 waves), both o per wave ----
  if (wv < 2 && lane < 49) {
    const int ci = __builtin_amdgcn_readfirstlane(wv);
    const int ph = lane / 7, pw = lane - (lane / 7) * 7;
    const uint* F2c = F2 + ci * 256 * 6;
    uint bwh[2][9];                                 // (bw2, 0) h2, uniform
#pragma unroll
    for (int o = 0; o < 2; ++o)
#pragma unroll
      for (int tp = 0; tp < 9; ++tp)
        bwh[o][tp] = pack_h2f(bw2[(o * 2 + ci) * 9 + tp], 0.0f);
    float pa[2][4] = {};
#pragma unroll
    for (int r = 0; r < 4; ++r) {
      uint4 fg[4]; uint sh2[4];
#pragma unroll
      for (int c = 0; c < 4; ++c) {
        const uint* sl = &F2c[((2 * ph + r) * 16 + (2 * pw + c)) * 6];
        uint2 a = *(const uint2*)sl;
        uint2 b = *(const uint2*)(sl + 2);
        fg[c] = make_uint4(a.x, a.y, b.x, b.y);
        sh2[c] = sl[4];
      }
#pragma unroll
      for (int dh = 0; dh < 2; ++dh) {
        const int tr = r - dh;
        if (tr < 0 || tr > 2) continue;
#pragma unroll
        for (int tc = 0; tc < 3; ++tc) {
          const int tap = tr * 3 + tc;
#pragma unroll
          for (int o = 0; o < 2; ++o) {
            const uint4 w = *(const uint4*)&WL[72 + ci * 72 + (tap * 2 + o) * 4];
#pragma unroll
            for (int dw = 0; dw < 2; ++dw) {
              const int c = tc + dw;
              float a2 = pa[o][dh * 2 + dw];
              a2 = fdot2f(sh2[c], bwh[o][tap], a2);
              a2 = fdot2f(fg[c].x, w.x, a2);
              a2 = fdot2f(fg[c].y, w.y, a2);
              a2 = fdot2f(fg[c].z, w.z, a2);
              a2 = fdot2f(fg[c].w, w.w, a2);
              pa[o][dh * 2 + dw] = a2;
            }
          }
        }
      }
    }
#pragma unroll
    for (int o = 0; o < 2; ++o)
      *(float4*)&P[((ci * 2 + o) * 49 + lane) * 4] =
          make_float4(pa[o][0], pa[o][1], pa[o][2], pa[o][3]);
  }
  __syncthreads();

  // ---- Phase C: sum ci, 2x2 maxpool, write (2,7,7) flat ----
  if (tid < 98) {
    const int o = tid / 49, pos = tid - o * 49;
    const float4 p0 = *(const float4*)&P[((0 * 2 + o) * 49 + pos) * 4];
    const float4 p1 = *(const float4*)&P[((1 * 2 + o) * 49 + pos) * 4];
    float m = fmaxf(fmaxf(p0.x + p1.x, p0.y + p1.y),
                    fmaxf(p0.z + p1.z, p0.w + p1.w));
    out[(size_t)blockIdx.x * 98 + tid] = m;
  }
}

extern "C" void kernel_launch(void* const* d_in, const int* in_sizes, int n_in,
                              void* d_out, int out_size, void* d_ws, size_t ws_size,
                              hipStream_t stream) {
  const float* x   = (const float*)d_in[0];
  const float* bw1 = (const float*)d_in[1];
  const float* sw1 = (const float*)d_in[2];
  const float* sc1 = (const float*)d_in[3];
  const float* bw2 = (const float*)d_in[4];
  const float* sw2 = (const float*)d_in[5];
  const float* sc2 = (const float*)d_in[6];
  float* out = (float*)d_out;
  const int B = in_sizes[0] / 784;  // 2048
  kan_fwd<<<B, TPB, 0, stream>>>(x, bw1, sw1, sc1, bw2, sw2, sc2, out);
}

// Round 5
// 108.838 us; speedup vs baseline: 2.3982x; 2.3982x over previous
//
#include <hip/hip_runtime.h>
#include <math.h>

typedef _Float16 half_t;
typedef _Float16 h2 __attribute__((ext_vector_type(2)));
typedef unsigned int uint;
typedef unsigned long long u64;

#define TPB 256

__device__ __forceinline__ uint pack_h2f(float a, float b) {
  half_t ha = (half_t)a, hb = (half_t)b;
  return (uint)__builtin_bit_cast(unsigned short, ha) |
         ((uint)__builtin_bit_cast(unsigned short, hb) << 16);
}

__device__ __forceinline__ float fdot2f(uint f, uint w, float acc) {
#if __has_builtin(__builtin_amdgcn_fdot2)
  return __builtin_amdgcn_fdot2(__builtin_bit_cast(h2, f),
                                __builtin_bit_cast(h2, w), acc, false);
#else
  h2 a = __builtin_bit_cast(h2, f), b = __builtin_bit_cast(h2, w);
  acc = fmaf((float)a.x, (float)b.x, acc);
  return fmaf((float)a.y, (float)b.y, acc);
#endif
}

struct Frag { uint d0, d1, d2, d3; float silu; };

// Uniform-knot cubic B-spline + silu; dense-8 fp16 fragment built in registers
// via a 128-bit shift scatter (validated in R2/R4, absmax 0.0156). Consumed
// immediately by the caller -> short live range, no spill pressure.
__device__ __forceinline__ Frag make_feat(float x) {
  Frag fr;
  float e = __expf(-x);
  fr.silu = x * __builtin_amdgcn_rcpf(1.0f + e);
  float s = fmaf(x, 2.5f, 5.5f);        // (x - (-2.2)) / 0.4
  float sf = floorf(s);
  float t = s - sf;
  int p = (int)sf - 3;                  // first nonzero basis index (may be <0)
  float omt = 1.0f - t, t2 = t * t;
  float B0 = (1.0f / 6.0f) * omt * omt * omt;
  float B3 = (1.0f / 6.0f) * t2 * t;
  float B1 = fmaf(0.5f * t, t2, 2.0f / 3.0f - t2);
  float B2 = 1.0f - B0 - B1 - B3;       // partition of unity
  u64 A = ((u64)pack_h2f(B2, B3) << 32) | pack_h2f(B0, B1);
  int n = p < 0 ? -p : 0;               // halves below 0: pre-drop
  A = (n >= 4) ? 0ull : (A >> (16 * n));
  int pc = p < 0 ? 0 : (p > 9 ? 9 : p);
  int sh = 16 * pc;                     // 0..144
  u64 lo = (sh < 64) ? (A << sh) : 0ull;
  u64 hi = (sh == 0) ? 0ull
         : (sh < 64) ? (A >> (64 - sh))
         : (sh < 128) ? (A << (sh - 64)) : 0ull;
  fr.d0 = (uint)lo; fr.d1 = (uint)(lo >> 32);
  fr.d2 = (uint)hi; fr.d3 = (uint)(hi >> 32);
  return fr;
}

// LDS map (dwords), SoA planes -> stride-1 lane access, zero bank conflicts:
//  F1 planes:  k*900 + idx        k=0..4 (d0,d1,d2,d3,silu), idx=row*30+col
//  F2 planes:  4500 + k*392 + idx idx = ch*196 + ph*14 + pw
//  WL1:        6460 + (o*9+tap)*4     L1 spline h2x4 (sw*scaler)
//  WL2:        6532 + (wid*9+tap)*4   L2 spline h2x4, wid=o*2+ci
//  P (stage>=3, aliases F1): 784 f32
#define F2B 4500
#define W1B 6460
#define W2B 6532

__global__ __launch_bounds__(TPB, 5) void kan_fwd(
    const float* __restrict__ x,
    const float* __restrict__ bw1, const float* __restrict__ sw1,
    const float* __restrict__ sc1,
    const float* __restrict__ bw2, const float* __restrict__ sw2,
    const float* __restrict__ sc2,
    float* __restrict__ out)
{
  __shared__ __align__(16) uint lds[6676];   // 26.7 KB -> 6 blocks/CU
  float* P = (float*)lds;

  const int tid = threadIdx.x;
  const float* xb = x + (size_t)blockIdx.x * 784;

  // ---- Phase 0: pack spline weights (sw*scaler -> fp16 pairs) into LDS ----
  if (tid < 54) {
    const float* sw; float scv; uint* dst;
    if (tid < 18) { sw = sw1 + tid * 8; scv = sc1[tid]; dst = &lds[W1B + tid * 4]; }
    else { int q = tid - 18; sw = sw2 + q * 8; scv = sc2[q]; dst = &lds[W2B + q * 4]; }
#pragma unroll
    for (int j = 0; j < 4; ++j)
      dst[j] = pack_h2f(sw[2 * j] * scv, sw[2 * j + 1] * scv);
  }

  // ---- Stage 1: features of padded 30x30 input into F1 planes ----
  for (int s1 = tid; s1 < 900; s1 += TPB) {
    int row = s1 / 30, col = s1 - row * 30;
    bool inter = ((uint)(row - 1) < 28u) && ((uint)(col - 1) < 28u);
    int xi = min(max((row - 1) * 28 + (col - 1), 0), 783);
    float xv = xb[xi];
    xv = inter ? xv : 0.0f;              // padding pixels get features of 0
    Frag fr = make_feat(xv);
    lds[s1] = fr.d0;
    lds[900 + s1] = fr.d1;
    lds[1800 + s1] = fr.d2;
    lds[2700 + s1] = fr.d3;
    lds[3600 + s1] = __float_as_uint(fr.silu);
  }
  __syncthreads();

  // ---- Stage 2: L1 conv (both o) per pool quad + maxpool + F2 features ----
  if (tid < 196) {
    const int ph = tid / 14, pw = tid - (tid / 14) * 14;
    float acc[2][4] = {};
#pragma unroll
    for (int r = 0; r < 4; ++r) {
#pragma unroll
      for (int c = 0; c < 4; ++c) {
        const int idx = (2 * ph + r) * 30 + (2 * pw + c);
        const uint d0 = lds[idx], d1 = lds[900 + idx];
        const uint d2 = lds[1800 + idx], d3 = lds[2700 + idx];
        const float sv = __uint_as_float(lds[3600 + idx]);
#pragma unroll
        for (int dh = 0; dh < 2; ++dh) {
          if (r - dh < 0 || r - dh > 2) continue;
#pragma unroll
          for (int dw = 0; dw < 2; ++dw) {
            if (c - dw < 0 || c - dw > 2) continue;
            const int tap = (r - dh) * 3 + (c - dw);
#pragma unroll
            for (int o = 0; o < 2; ++o) {
              const uint4 w = *(const uint4*)&lds[W1B + (o * 9 + tap) * 4];
              float a = acc[o][dh * 2 + dw];
              a = fmaf(sv, bw1[o * 9 + tap], a);   // uniform -> s_load
              a = fdot2f(d0, w.x, a);
              a = fdot2f(d1, w.y, a);
              a = fdot2f(d2, w.z, a);
              a = fdot2f(d3, w.w, a);
              acc[o][dh * 2 + dw] = a;
            }
          }
        }
      }
    }
#pragma unroll
    for (int o = 0; o < 2; ++o) {
      float m = fmaxf(fmaxf(acc[o][0], acc[o][1]), fmaxf(acc[o][2], acc[o][3]));
      Frag fm = make_feat(m);
      const int fi = o * 196 + tid;
      lds[F2B + fi] = fm.d0;
      lds[F2B + 392 + fi] = fm.d1;
      lds[F2B + 784 + fi] = fm.d2;
      lds[F2B + 1176 + fi] = fm.d3;
      lds[F2B + 1568 + fi] = __float_as_uint(fm.silu);
    }
  }
  __syncthreads();

  // ---- Stage 3: L2 conv; wave wid=(o*2+ci), lane = 7x7 pool position ----
  {
    const int wid = __builtin_amdgcn_readfirstlane(tid >> 6);
    const int lane = tid & 63;
    if (lane < 49) {
      const int o = wid >> 1, ci = wid & 1;
      const int ph = lane / 7, pw = lane - (lane / 7) * 7;
      // features of x=0 (padding): halves 2..5 = {1/48, 23/48, 23/48, 1/48}
      const uint F0d1 = pack_h2f(1.0f / 48.0f, 23.0f / 48.0f);
      const uint F0d2 = pack_h2f(23.0f / 48.0f, 1.0f / 48.0f);
      float pa[4] = {};
#pragma unroll
      for (int r = 0; r < 4; ++r) {
#pragma unroll
        for (int c = 0; c < 4; ++c) {
          int row = 2 * ph + r - 1, col = 2 * pw + c - 1;
          bool ok = ((uint)row < 14u) && ((uint)col < 14u);
          int rcl = min(max(row, 0), 13), ccl = min(max(col, 0), 13);
          const int idx = ci * 196 + rcl * 14 + ccl;
          uint d0 = lds[F2B + idx], d1 = lds[F2B + 392 + idx];
          uint d2 = lds[F2B + 784 + idx], d3 = lds[F2B + 1176 + idx];
          float sv = __uint_as_float(lds[F2B + 1568 + idx]);
          d0 = ok ? d0 : 0u;   d1 = ok ? d1 : F0d1;
          d2 = ok ? d2 : F0d2; d3 = ok ? d3 : 0u;
          sv = ok ? sv : 0.0f;                   // silu(0) = 0
#pragma unroll
          for (int dh = 0; dh < 2; ++dh) {
            if (r - dh < 0 || r - dh > 2) continue;
#pragma unroll
            for (int dw = 0; dw < 2; ++dw) {
              if (c - dw < 0 || c - dw > 2) continue;
              const int tap = (r - dh) * 3 + (c - dw);
              const uint4 w = *(const uint4*)&lds[W2B + (wid * 9 + tap) * 4];
              float a = pa[dh * 2 + dw];
              a = fmaf(sv, bw2[wid * 9 + tap], a);  // uniform -> s_load
              a = fdot2f(d0, w.x, a);
              a = fdot2f(d1, w.y, a);
              a = fdot2f(d2, w.z, a);
              a = fdot2f(d3, w.w, a);
              pa[dh * 2 + dw] = a;
            }
          }
        }
      }
      *(float4*)&P[(wid * 49 + lane) * 4] = make_float4(pa[0], pa[1], pa[2], pa[3]);
    }
  }
  __syncthreads();

  // ---- Stage 4: sum over ci, 2x2 maxpool, write (2,7,7) flat ----
  if (tid < 98) {
    const int o = tid / 49, pos = tid - o * 49;
    const float4 p0 = *(const float4*)&P[((o * 2 + 0) * 49 + pos) * 4];
    const float4 p1 = *(const float4*)&P[((o * 2 + 1) * 49 + pos) * 4];
    float m = fmaxf(fmaxf(p0.x + p1.x, p0.y + p1.y),
                    fmaxf(p0.z + p1.z, p0.w + p1.w));
    out[(size_t)blockIdx.x * 98 + tid] = m;
  }
}

extern "C" void kernel_launch(void* const* d_in, const int* in_sizes, int n_in,
                              void* d_out, int out_size, void* d_ws, size_t ws_size,
                              hipStream_t stream) {
  const float* x   = (const float*)d_in[0];
  const float* bw1 = (const float*)d_in[1];
  const float* sw1 = (const float*)d_in[2];
  const float* sc1 = (const float*)d_in[3];
  const float* bw2 = (const float*)d_in[4];
  const float* sw2 = (const float*)d_in[5];
  const float* sc2 = (const float*)d_in[6];
  float* out = (float*)d_out;
  const int B = in_sizes[0] / 784;  // 2048
  kan_fwd<<<B, TPB, 0, stream>>>(x, bw1, sw1, sc1, bw2, sw2, sc2, out);
}

// Round 7
// 85.101 us; speedup vs baseline: 3.0671x; 1.2789x over previous
//
#include <hip/hip_runtime.h>
#include <math.h>

typedef _Float16 half_t;
typedef _Float16 h2 __attribute__((ext_vector_type(2)));
typedef unsigned int uint;
typedef unsigned long long u64;

#define TPB 256

// pack two floats into a half2 bit pattern
__device__ __forceinline__ uint pack_h2f(float a, float b) {
  half_t ha = (half_t)a, hb = (half_t)b;
  unsigned short ua = __builtin_bit_cast(unsigned short, ha);
  unsigned short ub = __builtin_bit_cast(unsigned short, hb);
  return (uint)ua | ((uint)ub << 16);
}

// acc += silu*bw + sum_g basis[g]*w[g]   (fp16 dot2 pairs, fp32 accumulate)
// w points at 5 uniform dwords: 4x half2 spline weights (*scaler), 1x f32 base_w
// NOTE: w is a GLOBAL pointer on purpose — uniform vector loads ride the TA/L1
// pipe and keep weight traffic OFF the LDS pipe (K2 vs K3 A/B evidence).
__device__ __forceinline__ float dot8(uint d0, uint d1, uint d2, uint d3,
                                      float sv, const uint* __restrict__ w,
                                      float acc) {
  acc = fmaf(sv, __uint_as_float(w[4]), acc);
#if __has_builtin(__builtin_amdgcn_fdot2)
  acc = __builtin_amdgcn_fdot2(__builtin_bit_cast(h2, d0), __builtin_bit_cast(h2, w[0]), acc, false);
  acc = __builtin_amdgcn_fdot2(__builtin_bit_cast(h2, d1), __builtin_bit_cast(h2, w[1]), acc, false);
  acc = __builtin_amdgcn_fdot2(__builtin_bit_cast(h2, d2), __builtin_bit_cast(h2, w[2]), acc, false);
  acc = __builtin_amdgcn_fdot2(__builtin_bit_cast(h2, d3), __builtin_bit_cast(h2, w[3]), acc, false);
#else
  uint dd[4] = {d0, d1, d2, d3};
#pragma unroll
  for (int k = 0; k < 4; ++k) {
    h2 f = __builtin_bit_cast(h2, dd[k]);
    h2 wv = __builtin_bit_cast(h2, w[k]);
    acc = fmaf((float)f.x, (float)wv.x, acc);
    acc = fmaf((float)f.y, (float)wv.y, acc);
  }
#endif
  return acc;
}

// Uniform-knot cubic B-spline + silu features -> 6-dword LDS slot.
// halves 0..7 = dense 8-basis (fp16), dword4 = silu (fp32), dword5 = pad.
// R7 change (the ONLY change vs the proven K2 kernel): the dense fragment is
// built in registers via a 128-bit shift scatter (numerics validated K4/K5,
// same absmax) and stored with 2x ds_write_b64 + 1x b32 — replacing K2's four
// scattered ds_write_b16 (the dominant bank-conflict source, 2.8M cycles).
__device__ __forceinline__ void feat_store(float x, uint* __restrict__ slot) {
  float e = __expf(-x);
  float silu = x * __builtin_amdgcn_rcpf(1.0f + e);
  float s = fmaf(x, 2.5f, 5.5f);       // (x - (-2.2)) / 0.4
  float sf = floorf(s);
  float t = s - sf;
  int p = (int)sf - 3;                 // first nonzero basis index (may be <0)
  float omt = 1.0f - t, t2 = t * t;
  float B0 = (1.0f / 6.0f) * omt * omt * omt;
  float B3 = (1.0f / 6.0f) * t2 * t;
  float B1 = fmaf(0.5f * t, t2, 2.0f / 3.0f - t2);
  float B2 = 1.0f - B0 - B1 - B3;      // partition of unity
  u64 A = ((u64)pack_h2f(B2, B3) << 32) | pack_h2f(B0, B1);
  int n = p < 0 ? -p : 0;              // halves below 0: pre-drop
  A = (n >= 4) ? 0ull : (A >> (16 * n));
  int pc = p < 0 ? 0 : (p > 9 ? 9 : p);
  int sh = 16 * pc;                    // 0..144
  u64 lo = (sh < 64) ? (A << sh) : 0ull;
  u64 hi = (sh == 0) ? 0ull
         : (sh < 64) ? (A >> (64 - sh))
         : (sh < 128) ? (A << (sh - 64)) : 0ull;
  *(uint2*)slot = make_uint2((uint)lo, (uint)(lo >> 32));
  *(uint2*)(slot + 2) = make_uint2((uint)hi, (uint)(hi >> 32));
  slot[4] = __float_as_uint(silu);
}

// Precompute packed fp16 weights into d_ws (global; read via TA pipe):
// W[t*5]        t=o*9+tap        (layer 1, 18 entries)
// W[90 + q*5]   q=(o*2+ci)*9+tap (layer 2, 36 entries)
__global__ void pack_w(const float* __restrict__ bw1, const float* __restrict__ sw1,
                       const float* __restrict__ sc1, const float* __restrict__ bw2,
                       const float* __restrict__ sw2, const float* __restrict__ sc2,
                       uint* __restrict__ W) {
  const int t = threadIdx.x;
  if (t < 18) {
    const float scv = sc1[t];
    uint* dst = W + t * 5;
#pragma unroll
    for (int j = 0; j < 4; ++j)
      dst[j] = pack_h2f(sw1[t * 8 + 2 * j] * scv, sw1[t * 8 + 2 * j + 1] * scv);
    dst[4] = __float_as_uint(bw1[t]);
  } else if (t < 54) {
    const int q = t - 18;
    const float scv = sc2[q];
    uint* dst = W + 90 + q * 5;
#pragma unroll
    for (int j = 0; j < 4; ++j)
      dst[j] = pack_h2f(sw2[q * 8 + 2 * j] * scv, sw2[q * 8 + 2 * j + 1] * scv);
    dst[4] = __float_as_uint(bw2[q]);
  }
}

__global__ __launch_bounds__(TPB, 5) void kan_fwd(
    const float* __restrict__ x, const uint* __restrict__ W,
    float* __restrict__ out)
{
  // 6 dwords (24 B) per pixel slot
  __shared__ __align__(16) uint lds[5400 + 2352];  // 31 KB -> 5 blocks/CU
  uint* F1 = lds;            // 900 slots (30x30 padded)
  uint* F2 = lds + 5400;     // 2 x 196 slots (14x14, unpadded)
  float* P = (float*)lds;    // stage>=3: 4*49*4 partials (F1 region is dead)

  const int tid = threadIdx.x;
  const float* xb = x + (size_t)blockIdx.x * 784;

  // ---- Stage 1: features of padded 30x30 input ----
  for (int ii = tid; ii < 900; ii += TPB) {
    int r = ii / 30, c = ii % 30;
    bool inter = ((uint)(r - 1) < 28u) && ((uint)(c - 1) < 28u);
    int xi = (r - 1) * 28 + (c - 1);
    xi = min(max(xi, 0), 783);
    float xv = xb[xi];
    xv = inter ? xv : 0.0f;              // padding pixels get features of 0
    feat_store(xv, F1 + ii * 6);
  }
  __syncthreads();

  // ---- Stage 2: layer-1 conv (2x2 pool quad per thread) + pool + features ----
  if (tid < 196) {
    const int ph = tid / 14, pw = tid % 14;
    float acc[2][4];
#pragma unroll
    for (int o = 0; o < 2; ++o)
#pragma unroll
      for (int q = 0; q < 4; ++q) acc[o][q] = 0.0f;
#pragma unroll
    for (int r = 0; r < 4; ++r) {
#pragma unroll
      for (int c = 0; c < 4; ++c) {
        const uint* sl = F1 + ((2 * ph + r) * 30 + (2 * pw + c)) * 6;
        uint2 a = *(const uint2*)sl;
        uint2 bq = *(const uint2*)(sl + 2);
        float sv = __uint_as_float(sl[4]);
#pragma unroll
        for (int dh = 0; dh < 2; ++dh) {
          if (r - dh < 0 || r - dh > 2) continue;
#pragma unroll
          for (int dw = 0; dw < 2; ++dw) {
            if (c - dw < 0 || c - dw > 2) continue;
            const int tap = (r - dh) * 3 + (c - dw);
#pragma unroll
            for (int o = 0; o < 2; ++o)
              acc[o][dh * 2 + dw] =
                  dot8(a.x, a.y, bq.x, bq.y, sv, W + (o * 9 + tap) * 5, acc[o][dh * 2 + dw]);
          }
        }
      }
    }
#pragma unroll
    for (int o = 0; o < 2; ++o) {
      float m = fmaxf(fmaxf(acc[o][0], acc[o][1]), fmaxf(acc[o][2], acc[o][3]));
      feat_store(m, F2 + (o * 196 + tid) * 6);
    }
  }
  __syncthreads();

  // ---- Stage 3: layer-2 conv; one wave per (o,ci), lane = 7x7 pool pos ----
  {
    const int wid = __builtin_amdgcn_readfirstlane(tid >> 6);  // = o*2+ci
    const int lane = tid & 63;
    // features of x=0 (padding): basis halves 2..5 = {1/48, 23/48, 23/48, 1/48}
    const uint F0d1 = pack_h2f(1.0f / 48.0f, 23.0f / 48.0f);
    const uint F0d2 = pack_h2f(23.0f / 48.0f, 1.0f / 48.0f);
    if (lane < 49) {
      const int ci = wid & 1;
      const int ph = lane / 7, pw = lane % 7;
      float pa[4] = {0.0f, 0.0f, 0.0f, 0.0f};
#pragma unroll
      for (int r = 0; r < 4; ++r) {
#pragma unroll
        for (int c = 0; c < 4; ++c) {
          int row = 2 * ph + r - 1, col = 2 * pw + c - 1;
          bool ok = ((uint)row < 14u) && ((uint)col < 14u);
          int rcl = min(max(row, 0), 13), ccl = min(max(col, 0), 13);
          const uint* sl = F2 + (ci * 196 + rcl * 14 + ccl) * 6;
          uint2 a = *(const uint2*)sl;
          uint2 bq = *(const uint2*)(sl + 2);
          float sv = ok ? __uint_as_float(sl[4]) : 0.0f;
          uint d0 = ok ? a.x : 0u;
          uint d1 = ok ? a.y : F0d1;
          uint d2 = ok ? bq.x : F0d2;
          uint d3 = ok ? bq.y : 0u;
#pragma unroll
          for (int dh = 0; dh < 2; ++dh) {
            if (r - dh < 0 || r - dh > 2) continue;
#pragma unroll
            for (int dw = 0; dw < 2; ++dw) {
              if (c - dw < 0 || c - dw > 2) continue;
              const int tap = (r - dh) * 3 + (c - dw);
              pa[dh * 2 + dw] =
                  dot8(d0, d1, d2, d3, sv, W + 90 + (wid * 9 + tap) * 5, pa[dh * 2 + dw]);
            }
          }
        }
      }
      *(float4*)&P[(wid * 49 + lane) * 4] = make_float4(pa[0], pa[1], pa[2], pa[3]);
    }
  }
  __syncthreads();

  // ---- Stage 4: sum input channels, 2x2 maxpool, write (2,7,7) flat ----
  if (tid < 98) {
    const int o = tid / 49, pos = tid % 49;
    const float4 p0 = *(const float4*)&P[((o * 2 + 0) * 49 + pos) * 4];
    const float4 p1 = *(const float4*)&P[((o * 2 + 1) * 49 + pos) * 4];
    float m = fmaxf(fmaxf(p0.x + p1.x, p0.y + p1.y), fmaxf(p0.z + p1.z, p0.w + p1.w));
    out[(size_t)blockIdx.x * 98 + tid] = m;
  }
}

extern "C" void kernel_launch(void* const* d_in, const int* in_sizes, int n_in,
                              void* d_out, int out_size, void* d_ws, size_t ws_size,
                              hipStream_t stream) {
  const float* x   = (const float*)d_in[0];
  const float* bw1 = (const float*)d_in[1];
  const float* sw1 = (const float*)d_in[2];
  const float* sc1 = (const float*)d_in[3];
  const float* bw2 = (const float*)d_in[4];
  const float* sw2 = (const float*)d_in[5];
  const float* sc2 = (const float*)d_in[6];
  float* out = (float*)d_out;
  uint* W = (uint*)d_ws;  // 270 dwords
  const int B = in_sizes[0] / 784;  // 2048
  pack_w<<<1, 64, 0, stream>>>(bw1, sw1, sc1, bw2, sw2, sc2, W);
  kan_fwd<<<B, TPB, 0, stream>>>(x, W, out);
}